// Round 5
// baseline (40.886 us; speedup 1.0000x reference)
//
#include <hip/hip_runtime.h>

// Problem constants (from reference)
#define B_      4
#define L_      512
#define S_      100
#define NG_     19
#define GS_     5
#define VOCAB_  6
#define HID_    512
#define HPOOL_  4
#define D_      64
#define ALL_    256      // HPOOL * D
#define FIREH_  32
#define MAXDIST_ 20.0f

typedef float f32x2 __attribute__((ext_vector_type(2)));
typedef float f32x4 __attribute__((ext_vector_type(4)));

#define CWST_   (NG_ * 24)            // 456 floats of coefficients per row
#define NROWS_  (B_ * L_)             // 2048
// ws layout (floats): [0 .. 12288) W2 (24x512); [12288 ..) cw (2048x456)
#define WS_W2_   0
#define WS_CW_   (24 * HID_)
#define WS_NEED_ ((size_t)(WS_CW_ + NROWS_ * CWST_) * 4)

// ===========================================================================
// Fast path K1: one launch computes W2 (blocks 0..47), and cw for all rows
// (blocks 48..303, 8 rows each; bias recomputed per block — 32 exp, trivial).
// ===========================================================================
__global__ __launch_bounds__(256) void k1_kernel(
    const int*   __restrict__ ids,       // (2048,100)
    const float* __restrict__ dist,      // (100,)
    const float* __restrict__ attn_w,    // (6,4)
    const float* __restrict__ value_emb, // (6,256)
    const float* __restrict__ ffn_w,     // (256,512)
    const float* __restrict__ fire_c,
    const float* __restrict__ fire_w1,
    const float* __restrict__ fire_w2,
    float* __restrict__ W2_out,          // ws + WS_W2_
    float* __restrict__ cw_out)          // ws + WS_CW_
{
  const int b = blockIdx.x;
  const int t = threadIdx.x;

  if (b < 48) {                          // ---- W2: q = b>>1, col = (b&1)*256+t
    const int q   = b >> 1;
    const int col = (b & 1) * 256 + t;
    const int v = q >> 2, h = q & 3;
    float acc = 0.f;
#pragma unroll
    for (int k = 0; k < D_; ++k)
      acc = fmaf(value_emb[v * ALL_ + h * D_ + k],
                 ffn_w[(h * D_ + k) * HID_ + col], acc);
    W2_out[q * HID_ + col] = acc;
    return;
  }

  // ---- cw blocks: 8 rows each
  const int cb = b - 48;                 // 0..255
  __shared__ float s_bias[S_];
  __shared__ float s_aw[VOCAB_ * HPOOL_];

  if (t < S_) {
    const float c = fmaxf(fire_c[0], 0.f);
    const float denom = logf(fmaf(c, MAXDIST_, 1.f));
    const float rel = logf(fmaf(c, dist[t], 1.f)) / denom;
    float acc = 0.f;
#pragma unroll
    for (int i = 0; i < FIREH_; ++i) {
      const float x = rel * fire_w1[i];
      acc = fmaf(x / (1.f + expf(-x)), fire_w2[i], acc);   // silu
    }
    s_bias[t] = acc;
  } else if (t >= 128 && t < 128 + VOCAB_ * HPOOL_) {
    s_aw[t - 128] = attn_w[t - 128];
  }
  __syncthreads();

  for (int task = t; task < 8 * NG_ * HPOOL_; task += 256) {   // 608 tasks
    const int r = task / 76;
    const int u = task - r * 76;
    const int n = u >> 2, h = u & 3;
    const int row = cb * 8 + r;

    int   idg[GS_];
    float p[GS_];
    float m = -1e30f;
#pragma unroll
    for (int g = 0; g < GS_; ++g) {
      idg[g] = ids[row * S_ + n * GS_ + g];
      p[g] = s_aw[idg[g] * HPOOL_ + h] + s_bias[n * GS_ + g];
      m = fmaxf(m, p[g]);
    }
    float s = 0.f;
#pragma unroll
    for (int g = 0; g < GS_; ++g) { p[g] = expf(p[g] - m); s += p[g]; }
    const float inv = 1.f / s;

    // dense 6-vocab column via compare-select (no runtime-indexed array)
    float* dst = cw_out + row * CWST_ + n * 24 + h;
#pragma unroll
    for (int v = 0; v < VOCAB_; ++v) {
      float acc = 0.f;
#pragma unroll
      for (int g = 0; g < GS_; ++g) acc += (idg[g] == v) ? p[g] : 0.f;
      dst[v * HPOOL_] = acc * inv;
    }
  }
}

// ===========================================================================
// Fast path K2: pure streamer. 1024 blocks x 256 threads, 2 rows per block.
// No LDS, no barriers, no divergence. cw/ids reads are wave-uniform from
// read-only restrict pointers -> scalar (s_load) path, free wrt VMEM/VALU.
// ===========================================================================
__global__ __launch_bounds__(256) void k2_kernel(
    const int*   __restrict__ ids,       // (2048,100)
    const float* __restrict__ embed_tab, // (6,512)
    const float* __restrict__ ffn_b,     // (512,)
    const float* __restrict__ W2,        // (24,512) from ws
    const float* __restrict__ cw,        // (2048,456) from ws
    float* __restrict__ out)             // (2048,24,512)
{
  const int blk = blockIdx.x;            // 0..1023
  const int t   = threadIdx.x;
  const int bl0 = blk * 2;

  f32x2 w2r[24];
#pragma unroll
  for (int q = 0; q < 24; ++q)
    w2r[q] = *(const f32x2*)&W2[q * HID_ + 2 * t];
  const f32x2 bb = *(const f32x2*)&ffn_b[2 * t];

#pragma unroll
  for (int r = 0; r < 2; ++r) {
    const int row = bl0 + r;
    const float* __restrict__ cwr = cw + row * CWST_;
    float* op = out + (size_t)row * 24 * HID_ + 2 * t;

    for (int n = 0; n < NG_; ++n) {
      f32x2 acc = bb;
#pragma unroll
      for (int q4 = 0; q4 < 6; ++q4) {
        const f32x4 c = *(const f32x4*)&cwr[n * 24 + q4 * 4];  // uniform -> s_load
        acc.x = fmaf(c.x, w2r[q4 * 4 + 0].x, acc.x);
        acc.y = fmaf(c.x, w2r[q4 * 4 + 0].y, acc.y);
        acc.x = fmaf(c.y, w2r[q4 * 4 + 1].x, acc.x);
        acc.y = fmaf(c.y, w2r[q4 * 4 + 1].y, acc.y);
        acc.x = fmaf(c.z, w2r[q4 * 4 + 2].x, acc.x);
        acc.y = fmaf(c.z, w2r[q4 * 4 + 2].y, acc.y);
        acc.x = fmaf(c.w, w2r[q4 * 4 + 3].x, acc.x);
        acc.y = fmaf(c.w, w2r[q4 * 4 + 3].y, acc.y);
      }
      *(f32x2*)(op + n * HID_) = acc;
    }

    // singles: rows 19..23 (uniform id -> s_load; embed_tab L1-hot)
#pragma unroll
    for (int j = 0; j < 5; ++j) {
      const int id = ids[row * S_ + NG_ * GS_ + j];
      *(f32x2*)(op + (NG_ + j) * HID_) =
          *(const f32x2*)&embed_tab[id * HID_ + 2 * t];
    }
  }
}

// ===========================================================================
// Fallback path (ws too small): proven round-2 kernels (31.5 us).
// ===========================================================================
__global__ __launch_bounds__(128) void prep_kernel(
    const float* __restrict__ dist, const float* __restrict__ value_emb,
    const float* __restrict__ ffn_w, const float* __restrict__ fire_c,
    const float* __restrict__ fire_w1, const float* __restrict__ fire_w2,
    float* __restrict__ bias_out, float* __restrict__ W2_out)
{
  const int b = blockIdx.x;
  const int t = threadIdx.x;
  if (b < VOCAB_ * HPOOL_ * 4) {
    const int q   = b >> 2;
    const int col = (b & 3) * 128 + t;
    const int v = q >> 2, h = q & 3;
    float acc = 0.f;
#pragma unroll
    for (int k = 0; k < D_; ++k)
      acc = fmaf(value_emb[v * ALL_ + h * D_ + k],
                 ffn_w[(h * D_ + k) * HID_ + col], acc);
    W2_out[q * HID_ + col] = acc;
  } else if (t < S_) {
    const float c = fmaxf(fire_c[0], 0.f);
    const float denom = logf(fmaf(c, MAXDIST_, 1.f));
    const float rel = logf(fmaf(c, dist[t], 1.f)) / denom;
    float acc = 0.f;
#pragma unroll
    for (int i = 0; i < FIREH_; ++i) {
      const float x = rel * fire_w1[i];
      acc = fmaf(x / (1.f + expf(-x)), fire_w2[i], acc);
    }
    bias_out[t] = acc;
  }
}

__global__ __launch_bounds__(256) void main_kernel(
    const int*   __restrict__ ids, const float* __restrict__ attn_w,
    const float* __restrict__ embed_tab, const float* __restrict__ ffn_b,
    const float* __restrict__ bias, const float* __restrict__ W2,
    float* __restrict__ out)
{
  const int bl = blockIdx.x;
  const int t  = threadIdx.x;
  __shared__ int s_ids[S_];
  __shared__ float s_bias[S_];
  __shared__ float s_aw[VOCAB_ * HPOOL_];
  __shared__ __align__(16) float s_cw[NG_][24];

  if (t < S_) s_ids[t] = ids[bl * S_ + t];
  else if (t >= 100 && t < 200) s_bias[t - 100] = bias[t - 100];
  else if (t >= 224 && t < 248) s_aw[t - 224] = attn_w[t - 224];
#pragma unroll
  for (int i = t; i < NG_ * 24; i += 256) ((float*)s_cw)[i] = 0.f;
  __syncthreads();

  if (t < NG_ * HPOOL_) {
    const int n = t >> 2, h = t & 3;
    int idg[GS_]; float p[GS_]; float m = -1e30f;
#pragma unroll
    for (int g = 0; g < GS_; ++g) {
      idg[g] = s_ids[n * GS_ + g];
      p[g] = s_aw[idg[g] * HPOOL_ + h] + s_bias[n * GS_ + g];
      m = fmaxf(m, p[g]);
    }
    float s = 0.f;
#pragma unroll
    for (int g = 0; g < GS_; ++g) { p[g] = expf(p[g] - m); s += p[g]; }
    const float inv = 1.f / s;
#pragma unroll
    for (int g = 0; g < GS_; ++g)
      s_cw[n][idg[g] * HPOOL_ + h] += p[g] * inv;
  }
  __syncthreads();

  f32x2 w2r[24];
#pragma unroll
  for (int q = 0; q < 24; ++q)
    w2r[q] = *(const f32x2*)&W2[q * HID_ + 2 * t];
  const f32x2 bb = *(const f32x2*)&ffn_b[2 * t];
  float* op = out + (size_t)bl * 24 * HID_ + 2 * t;

  for (int n = 0; n < NG_; ++n) {
    f32x2 acc = bb;
    const f32x4* cw4 = (const f32x4*)s_cw[n];
#pragma unroll
    for (int q4 = 0; q4 < 6; ++q4) {
      const f32x4 c = cw4[q4];
      acc.x = fmaf(c.x, w2r[q4 * 4 + 0].x, acc.x);
      acc.y = fmaf(c.x, w2r[q4 * 4 + 0].y, acc.y);
      acc.x = fmaf(c.y, w2r[q4 * 4 + 1].x, acc.x);
      acc.y = fmaf(c.y, w2r[q4 * 4 + 1].y, acc.y);
      acc.x = fmaf(c.z, w2r[q4 * 4 + 2].x, acc.x);
      acc.y = fmaf(c.z, w2r[q4 * 4 + 2].y, acc.y);
      acc.x = fmaf(c.w, w2r[q4 * 4 + 3].x, acc.x);
      acc.y = fmaf(c.w, w2r[q4 * 4 + 3].y, acc.y);
    }
    *(f32x2*)(op + n * HID_) = acc;
  }
#pragma unroll
  for (int j = 0; j < 5; ++j) {
    const int id = s_ids[NG_ * GS_ + j];
    *(f32x2*)(op + (NG_ + j) * HID_) =
        *(const f32x2*)&embed_tab[id * HID_ + 2 * t];
  }
}

// ---------------------------------------------------------------------------
extern "C" void kernel_launch(void* const* d_in, const int* in_sizes, int n_in,
                              void* d_out, int out_size, void* d_ws, size_t ws_size,
                              hipStream_t stream) {
  const int*   src_ids = (const int*)  d_in[0];
  const float* dist    = (const float*)d_in[1];
  const float* attn_w  = (const float*)d_in[2];
  const float* valemb  = (const float*)d_in[3];
  const float* ffn_w   = (const float*)d_in[4];
  const float* ffn_b   = (const float*)d_in[5];
  const float* emb_tab = (const float*)d_in[6];
  const float* fire_c  = (const float*)d_in[7];
  const float* fire_w1 = (const float*)d_in[8];
  const float* fire_w2 = (const float*)d_in[9];

  float* out = (float*)d_out;
  float* ws  = (float*)d_ws;

  if (ws_size >= WS_NEED_) {
    float* W2 = ws + WS_W2_;
    float* cw = ws + WS_CW_;
    hipLaunchKernelGGL(k1_kernel, dim3(48 + 256), dim3(256), 0, stream,
                       src_ids, dist, attn_w, valemb, ffn_w,
                       fire_c, fire_w1, fire_w2, W2, cw);
    hipLaunchKernelGGL(k2_kernel, dim3(NROWS_ / 2), dim3(256), 0, stream,
                       src_ids, emb_tab, ffn_b, W2, cw, out);
  } else {
    float* bias = ws;
    float* W2   = ws + 128;
    hipLaunchKernelGGL(prep_kernel, dim3(97), dim3(128), 0, stream,
                       dist, valemb, ffn_w, fire_c, fire_w1, fire_w2, bias, W2);
    hipLaunchKernelGGL(main_kernel, dim3(NROWS_), dim3(256), 0, stream,
                       src_ids, attn_w, emb_tab, ffn_b, bias, W2, out);
  }
}

// Round 6
// 32.170 us; speedup vs baseline: 1.2709x; 1.2709x over previous
//
#include <hip/hip_runtime.h>

// Problem constants (from reference)
#define B_      4
#define L_      512
#define S_      100
#define NG_     19
#define GS_     5
#define VOCAB_  6
#define HID_    512
#define HPOOL_  4
#define D_      64
#define ALL_    256      // HPOOL * D
#define FIREH_  32
#define MAXDIST_ 20.0f

typedef float f32x2 __attribute__((ext_vector_type(2)));
typedef float f32x4 __attribute__((ext_vector_type(4)));

#define NROWS_  (B_ * L_)             // 2048
// ws layout (floats): [0..99] bias, [128..128+24*512) W2 (q = v*4+h major, d minor)

// ---------------------------------------------------------------------------
// K1: precompute FIRE bias (100 values) and W2[v*4+h][d] = value_emb slice @ ffn_w
// ---------------------------------------------------------------------------
__global__ __launch_bounds__(128) void prep_kernel(
    const float* __restrict__ dist,      // (100,)
    const float* __restrict__ value_emb, // (6,256)
    const float* __restrict__ ffn_w,     // (256,512)
    const float* __restrict__ fire_c,
    const float* __restrict__ fire_w1,
    const float* __restrict__ fire_w2,
    float* __restrict__ bias_out,        // ws + 0
    float* __restrict__ W2_out)          // ws + 128
{
  const int b = blockIdx.x;
  const int t = threadIdx.x;
  if (b < VOCAB_ * HPOOL_ * 4) {
    const int q   = b >> 2;            // 0..23
    const int col = (b & 3) * 128 + t; // 0..511
    const int v = q >> 2, h = q & 3;
    float acc = 0.f;
#pragma unroll
    for (int k = 0; k < D_; ++k)
      acc = fmaf(value_emb[v * ALL_ + h * D_ + k],
                 ffn_w[(h * D_ + k) * HID_ + col], acc);
    W2_out[q * HID_ + col] = acc;
  } else if (t < S_) {
    const float c = fmaxf(fire_c[0], 0.f);
    const float denom = logf(fmaf(c, MAXDIST_, 1.f));
    const float rel = logf(fmaf(c, dist[t], 1.f)) / denom;
    float acc = 0.f;
#pragma unroll
    for (int i = 0; i < FIREH_; ++i) {
      const float x = rel * fire_w1[i];
      acc = fmaf(x / (1.f + __expf(-x)), fire_w2[i], acc);   // silu
    }
    bias_out[t] = acc;
  }
}

// ---------------------------------------------------------------------------
// K2: main. One block per (b,l) row (round-2 structure, best known).
// 256 threads; thread t owns output cols 2t..2t+1.
// Phase B ILP fix: 4 partial accumulator pairs -> dependency chain per n drops
// from 24 FMAs to 6; singles stores hoisted ahead of the n-loop.
// ---------------------------------------------------------------------------
#define QB(C, BASE)                                                    \
  a0.x = fmaf(C.x, w2r[BASE + 0].x, a0.x);                             \
  a0.y = fmaf(C.x, w2r[BASE + 0].y, a0.y);                             \
  a1.x = fmaf(C.y, w2r[BASE + 1].x, a1.x);                             \
  a1.y = fmaf(C.y, w2r[BASE + 1].y, a1.y);                             \
  a2.x = fmaf(C.z, w2r[BASE + 2].x, a2.x);                             \
  a2.y = fmaf(C.z, w2r[BASE + 2].y, a2.y);                             \
  a3.x = fmaf(C.w, w2r[BASE + 3].x, a3.x);                             \
  a3.y = fmaf(C.w, w2r[BASE + 3].y, a3.y);

__global__ __launch_bounds__(256, 6) void main_kernel(
    const int*   __restrict__ ids,       // (B*L, 100)
    const float* __restrict__ attn_w,    // (6,4)
    const float* __restrict__ embed_tab, // (6,512)
    const float* __restrict__ ffn_b,     // (512,)
    const float* __restrict__ bias,      // (100,) from ws
    const float* __restrict__ W2,        // (24,512) from ws
    float* __restrict__ out)             // (B*L, 24, 512)
{
  const int bl = blockIdx.x;
  const int t  = threadIdx.x;

  __shared__ int   s_ids[S_];
  __shared__ float s_bias[S_];
  __shared__ float s_aw[VOCAB_ * HPOOL_];
  __shared__ __align__(16) float s_cw[NG_][24];

  if (t < S_) s_ids[t] = ids[bl * S_ + t];
  else if (t >= 100 && t < 200) s_bias[t - 100] = bias[t - 100];
  else if (t >= 224 && t < 248) s_aw[t - 224] = attn_w[t - 224];

  // hoist W2/ffn_b loads before the barrier: latency hides under phase A
  f32x2 w2r[24];
#pragma unroll
  for (int q = 0; q < 24; ++q)
    w2r[q] = *(const f32x2*)&W2[q * HID_ + 2 * t];
  const f32x2 bb = *(const f32x2*)&ffn_b[2 * t];

#pragma unroll
  for (int i = t; i < NG_ * 24; i += 256) ((float*)s_cw)[i] = 0.f;
  __syncthreads();

  // --- phase A: 76 threads ---
  if (t < NG_ * HPOOL_) {
    const int n = t >> 2, h = t & 3;
    int idg[GS_]; float p[GS_]; float m = -1e30f;
#pragma unroll
    for (int g = 0; g < GS_; ++g) {
      idg[g] = s_ids[n * GS_ + g];
      p[g] = s_aw[idg[g] * HPOOL_ + h] + s_bias[n * GS_ + g];
      m = fmaxf(m, p[g]);
    }
    float s = 0.f;
#pragma unroll
    for (int g = 0; g < GS_; ++g) { p[g] = __expf(p[g] - m); s += p[g]; }
    const float inv = 1.f / s;
#pragma unroll
    for (int g = 0; g < GS_; ++g)
      s_cw[n][idg[g] * HPOOL_ + h] += p[g] * inv;   // exclusive ownership
  }
  __syncthreads();

  float* op = out + (size_t)bl * 24 * HID_ + 2 * t;

  // --- singles FIRST: independent work primes the store pipe ---
#pragma unroll
  for (int j = 0; j < 5; ++j) {
    const int id = s_ids[NG_ * GS_ + j];
    *(f32x2*)(op + (NG_ + j) * HID_) =
        *(const f32x2*)&embed_tab[id * HID_ + 2 * t];
  }

  // --- phase B: 4 partial accumulator pairs (chains of 6, not 24) ---
  for (int n = 0; n < NG_; ++n) {
    const f32x4* cw4 = (const f32x4*)s_cw[n];
    const f32x4 c0 = cw4[0], c1 = cw4[1], c2 = cw4[2],
                c3 = cw4[3], c4 = cw4[4], c5 = cw4[5];
    f32x2 a0 = bb;
    f32x2 a1 = {0.f, 0.f}, a2 = {0.f, 0.f}, a3 = {0.f, 0.f};
    QB(c0, 0) QB(c1, 4) QB(c2, 8) QB(c3, 12) QB(c4, 16) QB(c5, 20)
    f32x2 acc;
    acc.x = (a0.x + a1.x) + (a2.x + a3.x);
    acc.y = (a0.y + a1.y) + (a2.y + a3.y);
    *(f32x2*)(op + n * HID_) = acc;
  }
}

// ---------------------------------------------------------------------------
extern "C" void kernel_launch(void* const* d_in, const int* in_sizes, int n_in,
                              void* d_out, int out_size, void* d_ws, size_t ws_size,
                              hipStream_t stream) {
  const int*   src_ids = (const int*)  d_in[0];
  const float* dist    = (const float*)d_in[1];
  const float* attn_w  = (const float*)d_in[2];
  const float* valemb  = (const float*)d_in[3];
  const float* ffn_w   = (const float*)d_in[4];
  const float* ffn_b   = (const float*)d_in[5];
  const float* emb_tab = (const float*)d_in[6];
  const float* fire_c  = (const float*)d_in[7];
  const float* fire_w1 = (const float*)d_in[8];
  const float* fire_w2 = (const float*)d_in[9];

  float* out  = (float*)d_out;
  float* ws   = (float*)d_ws;
  float* bias = ws;         // 100 floats
  float* W2   = ws + 128;   // 24*512 floats (16B-aligned)

  hipLaunchKernelGGL(prep_kernel, dim3(97), dim3(128), 0, stream,
                     dist, valemb, ffn_w, fire_c, fire_w1, fire_w2, bias, W2);
  hipLaunchKernelGGL(main_kernel, dim3(NROWS_), dim3(256), 0, stream,
                     src_ids, attn_w, emb_tab, ffn_b, bias, W2, out);
}